// Round 5
// baseline (121.486 us; speedup 1.0000x reference)
//
#include <hip/hip_runtime.h>
#include <hip/hip_bf16.h>

#define LN_EPS 1e-5f
#define BB 32        // batch
#define NI 200       // attended nodes
#define NIP 208      // padded to 13*16
#define DD 64        // feature dim

typedef __attribute__((ext_vector_type(8))) short bf16x8;
typedef __attribute__((ext_vector_type(4))) short bf16x4;
typedef __attribute__((ext_vector_type(4))) float f32x4;

__device__ __forceinline__ float leaky(float x) { return fmaxf(x, 0.01f * x); }
__device__ __forceinline__ short f2bf(float x) {
  __hip_bfloat16 h = __float2bfloat16(x);
  return *reinterpret_cast<short*>(&h);
}
__device__ __forceinline__ float bf2fs(short s) {
  unsigned u = ((unsigned)(unsigned short)s) << 16;
  return __uint_as_float(u);
}
__device__ __forceinline__ bf16x8 sq8(bf16x8 a) {
  bf16x8 r;
#pragma unroll
  for (int k = 0; k < 8; k++) { float f = bf2fs(a[k]); r[k] = f2bf(f * f); }
  return r;
}

// workspace layout (float offsets)
#define WS_UA   0                        // [BB][NI][DD] fp32 ua
#define WS_SK   (WS_UA + BB*NI*DD)       // [2][BB][NIP] sk' = sk+ck (pad=0)
#define WS_SS   (WS_SK + 2*BB*NIP)       // [BB][NIP][8]: sq1',rm1,iv1,sq2',rm2,iv2,0,0

__device__ __forceinline__ void reduce2(float& a, float& b) {
#pragma unroll
  for (int m = 1; m < 64; m <<= 1) { a += __shfl_xor(a, m, 64); b += __shfl_xor(b, m, 64); }
}
__device__ __forceinline__ float reduce1(float a) {
#pragma unroll
  for (int m = 1; m < 64; m <<= 1) a += __shfl_xor(a, m, 64);
  return a;
}

// kA: one block per batch (512 thr, 8 waves): all LNs + GEMVs + scores + softmax stats.
__global__ void __launch_bounds__(512) gat_kA(const float* __restrict__ emb,
                                              const float* __restrict__ lw,
                                              const float* __restrict__ lb,
                                              const float* __restrict__ W1,
                                              const float* __restrict__ W1b,
                                              const float* __restrict__ W2,
                                              const float* __restrict__ W2b,
                                              const float* __restrict__ a1,
                                              const float* __restrict__ a1b,
                                              const float* __restrict__ a2,
                                              const float* __restrict__ a2b,
                                              float* __restrict__ ws,
                                              float* __restrict__ out) {
  int b = blockIdx.x, tid = threadIdx.x, wv = tid >> 6, lane = tid & 63;
  __shared__ float sua[NI][65];     // raw ua, odd stride -> conflict-free
  __shared__ float v_sh[6][64];     // vq1,vk1,vi1,vq2,vk2,vi2
  __shared__ float cred[6];         // Wb·a_c per gemv
  __shared__ float tf[2];           // t per head
  __shared__ float iid_sh[64];
  __shared__ float sk_sh[2][NI];

  // ---- GEMVs: wave g<6 computes v_g = W^T a_c and cred_g = Wb·a_c ----
  if (wv < 6) {
    int h = wv / 3, c = wv - h * 3;
    const float* W  = h ? W2 : W1;
    const float* Wb = h ? W2b : W1b;
    const float* A  = h ? a2 : a1;
    float acc = 0;
#pragma unroll 8
    for (int d = 0; d < 64; d++) acc = fmaf(W[d * 64 + lane], A[c * 64 + d], acc);
    v_sh[wv][lane] = acc;
    float cr = reduce1(Wb[lane] * A[c * 64 + lane]);
    if (lane == 0) cred[wv] = cr;
  }

  // ---- LayerNorms: u once per wave; rows 1..201 split across 8 waves ----
  float w = lw[lane], bi = lb[lane];
  auto lnrow = [&](int n) -> float {
    float x = emb[(size_t)(b * 202 + n) * 64 + lane];
    float s = x, s2 = x * x;
    reduce2(s, s2);
    float mu = s * (1.f / 64);
    float var = fmaxf(s2 * (1.f / 64) - mu * mu, 0.f);
    return (x - mu) * rsqrtf(var + LN_EPS) * w + bi;
  };
  float u = lnrow(0);
  for (int n = 1 + wv; n <= 201; n += 8) {
    float y = lnrow(n);
    if (n == 1) {
      iid_sh[lane] = y;
      out[(size_t)(b * 201) * 64 + lane] = leaky(u * y);   // ui row
    } else {
      int i = n - 2;
      float a = u * y;
      sua[i][lane] = a;
      ws[WS_UA + (size_t)(b * NI + i) * 64 + lane] = a;
    }
  }
  __syncthreads();

  // ---- t consts (waves 0,1) + score dots (threads 0..399) ----
  if (wv < 2) {
    float p = reduce1(iid_sh[lane] * v_sh[wv * 3 + 2][lane]);
    if (lane == 0) tf[wv] = p + cred[wv * 3 + 2] + (wv ? a2b[0] : a1b[0]);
  }
  float sq = 0;
  int h = (tid >= 200), i = tid - h * 200;
  if (tid < 400) {
    const float* vq = v_sh[h * 3 + 0];
    const float* vk = v_sh[h * 3 + 1];
    float sk = 0;
#pragma unroll 8
    for (int d = 0; d < 64; d++) {
      float x = sua[i][d];
      sq = fmaf(x, vq[d], sq);
      sk = fmaf(x, vk[d], sk);
    }
    sk += cred[h * 3 + 1];
    sk_sh[h][i] = sk;
  }
  __syncthreads();

  // ---- softmax row stats ----
  if (tid < 400) {
    float base = sq + cred[h * 3] + tf[h];
    const float* skv = sk_sh[h];
    float mx = -1e30f;
    for (int j = 0; j < NI; j++) mx = fmaxf(mx, skv[j]);
    float rm = leaky(base + mx);   // leaky monotone
    float den = 0.f;
#pragma unroll 4
    for (int j = 0; j < NI; j++) {
      float s = base + skv[j];
      den += __expf(fmaxf(s, 0.01f * s) - rm);
    }
    float* ss = ws + WS_SS + (size_t)(b * NIP + i) * 8 + 3 * h;
    ss[0] = base; ss[1] = rm; ss[2] = 1.0f / den;
    ws[WS_SK + (size_t)(h * BB + b) * NIP + i] = sk_sh[h][i];
  } else if (tid >= 400 && tid < 408) {   // zero pad rows 200..207
    int ip = tid - 400 + 200;
    float* ss = ws + WS_SS + (size_t)(b * NIP + ip) * 8;
#pragma unroll
    for (int k = 0; k < 8; k++) ss[k] = 0.f;
    ws[WS_SK + (size_t)(0 * BB + b) * NIP + ip] = 0.f;
    ws[WS_SK + (size_t)(1 * BB + b) * NIP + ip] = 0.f;
  }
}

// kB: MFMA attention-value (unchanged from round 4). grid (13, BB) x 256.
__global__ void __launch_bounds__(256) gat_kB(const float* __restrict__ ws,
                                              const float* __restrict__ lw,
                                              const float* __restrict__ lb,
                                              float* __restrict__ out) {
  int b = blockIdx.y, jt = blockIdx.x, tid = threadIdx.x;
  int wv = tid >> 6, lane = tid & 63, q = lane >> 4, col = lane & 15;
  __shared__ __align__(16) short sUA[13 * 2 * 64 * 8];
  __shared__ __align__(16) short sUAT[7 * 4 * 64 * 8];
  __shared__ __align__(16) short sG[7 * 64 * 8];
  __shared__ float sPart[4][2][16];

  const float* uab = ws + WS_UA + (size_t)b * NI * DD;

  for (int idx = tid; idx < 13 * 2 * 64; idx += 256) {
    int itile = idx >> 7, rem = idx & 127, kh = rem >> 6, ln = rem & 63;
    int node = itile * 16 + (ln & 15);
    int dbase = kh * 32 + (ln >> 4) * 8;
    bf16x8 pk;
    if (node < NI) {
      const float4 p0 = *(const float4*)(uab + node * 64 + dbase);
      const float4 p1 = *(const float4*)(uab + node * 64 + dbase + 4);
      pk[0] = f2bf(p0.x); pk[1] = f2bf(p0.y); pk[2] = f2bf(p0.z); pk[3] = f2bf(p0.w);
      pk[4] = f2bf(p1.x); pk[5] = f2bf(p1.y); pk[6] = f2bf(p1.z); pk[7] = f2bf(p1.w);
    } else {
#pragma unroll
      for (int k = 0; k < 8; k++) pk[k] = 0;
    }
    *(bf16x8*)(sUA + idx * 8) = pk;
  }
  {
    int d = tid & 63, ir = tid >> 6;
#pragma unroll
    for (int p = 0; p < 7; p++) {
      int i0 = p * 32 + ir * 8;
      bf16x8 pk;
#pragma unroll
      for (int u = 0; u < 8; u++)
        pk[u] = (i0 + u < NI) ? f2bf(uab[(i0 + u) * 64 + d]) : (short)0;
      int off = ((p * 4 + (d >> 4)) * 64 + ((d & 15) + 16 * ir)) * 8;
      *(bf16x8*)(sUAT + off) = pk;
    }
  }
  ((int*)(sG + (6 * 64 + 32) * 8))[tid] = 0;
  __syncthreads();

  bf16x8 bf0 = *(bf16x8*)(sUA + ((jt * 2 + 0) * 64 + lane) * 8);
  bf16x8 bf1 = *(bf16x8*)(sUA + ((jt * 2 + 1) * 64 + lane) * 8);
  bf16x8 b2f0 = sq8(bf0), b2f1 = sq8(bf1);
  int jglob = jt * 16 + col;
  float skj1 = ws[WS_SK + (size_t)(0 * BB + b) * NIP + jglob];
  float skj2 = ws[WS_SK + (size_t)(1 * BB + b) * NIP + jglob];
  float mpart = 0.f, spart = 0.f;

  for (int it = wv; it < 13; it += 4) {
    bf16x8 af0 = *(bf16x8*)(sUA + ((it * 2 + 0) * 64 + lane) * 8);
    bf16x8 af1 = *(bf16x8*)(sUA + ((it * 2 + 1) * 64 + lane) * 8);
    bf16x8 a2f0 = sq8(af0), a2f1 = sq8(af1);
    f32x4 s = {0, 0, 0, 0}, t = {0, 0, 0, 0};
    s = __builtin_amdgcn_mfma_f32_16x16x32_bf16(af0, bf0, s, 0, 0, 0);
    s = __builtin_amdgcn_mfma_f32_16x16x32_bf16(af1, bf1, s, 0, 0, 0);
    t = __builtin_amdgcn_mfma_f32_16x16x32_bf16(a2f0, b2f0, t, 0, 0, 0);
    t = __builtin_amdgcn_mfma_f32_16x16x32_bf16(a2f1, b2f1, t, 0, 0, 0);
    bf16x4 gp;
#pragma unroll
    for (int r = 0; r < 4; r++) {
      int i = it * 16 + q * 4 + r;
      const f32x4 s0 = *(const f32x4*)(ws + WS_SS + (size_t)(b * NIP + i) * 8);
      const f32x4 s1 = *(const f32x4*)(ws + WS_SS + (size_t)(b * NIP + i) * 8 + 4);
      float mu = s[r] * (1.f / 64);
      float var = fmaxf(t[r] * (1.f / 64) - mu * mu, 0.f);
      float inv = rsqrtf(var + LN_EPS);
      float sc1 = s0.x + skj1;
      float e1 = __expf(fmaxf(sc1, 0.01f * sc1) - s0.y) * s0.z;
      float sc2 = s0.w + skj2;
      float e2 = __expf(fmaxf(sc2, 0.01f * sc2) - s1.x) * s1.y;
      float c = 0.5f * (e1 + e2);
      float g = c * inv;
      mpart = fmaf(g, mu, mpart);
      spart += c;
      gp[r] = f2bf(g);
    }
    int kl = (it & 1) * 16 + q * 4;
    int off = ((it >> 1) * 64 + (col + 16 * (kl >> 3))) * 8 + (kl & 7);
    *(bf16x4*)(sG + off) = gp;
  }
  mpart += __shfl_xor(mpart, 16, 64); mpart += __shfl_xor(mpart, 32, 64);
  spart += __shfl_xor(spart, 16, 64); spart += __shfl_xor(spart, 32, 64);
  if (lane < 16) { sPart[wv][0][lane] = mpart; sPart[wv][1][lane] = spart; }
  __syncthreads();

  f32x4 acc = {0, 0, 0, 0};
#pragma unroll
  for (int kt = 0; kt < 7; kt++) {
    bf16x8 ga = *(bf16x8*)(sG + (kt * 64 + lane) * 8);
    bf16x8 ub = *(bf16x8*)(sUAT + ((kt * 4 + wv) * 64 + lane) * 8);
    acc = __builtin_amdgcn_mfma_f32_16x16x32_bf16(ga, ub, acc, 0, 0, 0);
  }
  int d = wv * 16 + col;
  float w = lw[d], bia = lb[d];
#pragma unroll
  for (int r = 0; r < 4; r++) {
    int jl = q * 4 + r, jg = jt * 16 + jl;
    if (jg < NI) {
      float m = sPart[0][0][jl] + sPart[1][0][jl] + sPart[2][0][jl] + sPart[3][0][jl];
      float S = sPart[0][1][jl] + sPart[1][1][jl] + sPart[2][1][jl] + sPart[3][1][jl];
      float uajd = uab[jg * 64 + d];
      float att = w * (uajd * acc[r] - m) + bia * S;
      out[(size_t)(b * 201 + 1 + jg) * 64 + d] = leaky(att);
    }
  }
}

extern "C" void kernel_launch(void* const* d_in, const int* in_sizes, int n_in,
                              void* d_out, int out_size, void* d_ws, size_t ws_size,
                              hipStream_t stream) {
  const float* emb = (const float*)d_in[0];
  const float* lw  = (const float*)d_in[1];
  const float* lb  = (const float*)d_in[2];
  const float* W1  = (const float*)d_in[3];
  const float* W1b = (const float*)d_in[4];
  const float* W2  = (const float*)d_in[5];
  const float* W2b = (const float*)d_in[6];
  const float* a1  = (const float*)d_in[7];
  const float* a1b = (const float*)d_in[8];
  const float* a2  = (const float*)d_in[9];
  const float* a2b = (const float*)d_in[10];
  float* ws = (float*)d_ws;
  float* out = (float*)d_out;

  gat_kA<<<dim3(BB), dim3(512), 0, stream>>>(emb, lw, lb, W1, W1b, W2, W2b,
                                             a1, a1b, a2, a2b, ws, out);
  gat_kB<<<dim3(13, BB), dim3(256), 0, stream>>>(ws, lw, lb, out);
}

// Round 6
// 100.700 us; speedup vs baseline: 1.2064x; 1.2064x over previous
//
#include <hip/hip_runtime.h>
#include <hip/hip_bf16.h>

#define LN_EPS 1e-5f
#define BB 32        // batch
#define NI 200       // attended nodes
#define NIP 208      // padded to 13*16
#define DD 64        // feature dim

typedef __attribute__((ext_vector_type(8))) short bf16x8;
typedef __attribute__((ext_vector_type(4))) short bf16x4;
typedef __attribute__((ext_vector_type(4))) float f32x4;

__device__ __forceinline__ float leaky(float x) { return fmaxf(x, 0.01f * x); }
__device__ __forceinline__ short f2bf(float x) {
  __hip_bfloat16 h = __float2bfloat16(x);
  return *reinterpret_cast<short*>(&h);
}
__device__ __forceinline__ float bf2fs(short s) {
  unsigned u = ((unsigned)(unsigned short)s) << 16;
  return __uint_as_float(u);
}
__device__ __forceinline__ bf16x8 sq8(bf16x8 a) {
  bf16x8 r;
#pragma unroll
  for (int k = 0; k < 8; k++) { float f = bf2fs(a[k]); r[k] = f2bf(f * f); }
  return r;
}

// workspace layout (float offsets)
#define WS_SC 0                     // [BB][NIP][4] raw {sq1,sk1,sq2,sk2}
#define WS_T  (WS_SC + BB*NIP*4)    // [BB][2] raw iid·vi dots
#define WS_CR (WS_T + BB*2)         // [6] cred = Wb·a_c (+2 pad)
#define WS_UB (WS_CR + 8)           // bf16 ua [BB][NI][64] (as ushort)

__device__ __forceinline__ void reduce2(float& a, float& b) {
#pragma unroll
  for (int m = 1; m < 64; m <<= 1) { a += __shfl_xor(a, m, 64); b += __shfl_xor(b, m, 64); }
}
__device__ __forceinline__ void reduce4(float& a, float& b, float& c, float& d) {
#pragma unroll
  for (int m = 1; m < 64; m <<= 1) {
    a += __shfl_xor(a, m, 64); b += __shfl_xor(b, m, 64);
    c += __shfl_xor(c, m, 64); d += __shfl_xor(d, m, 64);
  }
}
__device__ __forceinline__ float reduce1(float a) {
#pragma unroll
  for (int m = 1; m < 64; m <<= 1) a += __shfl_xor(a, m, 64);
  return a;
}
__device__ __forceinline__ void rmax2(float& a, float& b) {
#pragma unroll
  for (int m = 1; m < 64; m <<= 1) {
    a = fmaxf(a, __shfl_xor(a, m, 64));
    b = fmaxf(b, __shfl_xor(b, m, 64));
  }
}

// kX: grid (51, BB) x 256. Wave wv handles node = bx*4+wv: LN + ua(bf16) + raw
// score dots. Waves 0-1 redundantly compute vq/vk GEMVs per block (L2-cheap).
// Block (0,b): vi GEMVs + t_raw; block (0,0): cred consts.
__global__ void __launch_bounds__(256) gat_kX(const float* __restrict__ emb,
                                              const float* __restrict__ lw,
                                              const float* __restrict__ lb,
                                              const float* __restrict__ W1,
                                              const float* __restrict__ W1b,
                                              const float* __restrict__ W2,
                                              const float* __restrict__ W2b,
                                              const float* __restrict__ a1,
                                              const float* __restrict__ a2,
                                              float* __restrict__ ws,
                                              float* __restrict__ out) {
  int b = blockIdx.y, tid = threadIdx.x, wv = tid >> 6, lane = tid & 63;
  int node = blockIdx.x * 4 + wv;
  __shared__ float v_sh[4][64];   // vq1,vk1,vq2,vk2
  __shared__ float vi_sh[2][64];  // vi1,vi2 (block x==0 only)
  __shared__ float iid_sh[64];

  float w = lw[lane], bi = lb[lane];
  auto lnrow = [&](int n) -> float {
    float x = emb[(size_t)(b * 202 + n) * 64 + lane];
    float s = x, s2 = x * x;
    reduce2(s, s2);
    float mu = s * (1.f / 64);
    float var = fmaxf(s2 * (1.f / 64) - mu * mu, 0.f);
    return (x - mu) * rsqrtf(var + LN_EPS) * w + bi;
  };
  float u = lnrow(0);
  float y = 0.f;
  if (node >= 1 && node <= 201) y = lnrow(node);
  if (node == 1) {
    iid_sh[lane] = y;
    out[(size_t)(b * 201) * 64 + lane] = leaky(u * y);   // ui row
  }
  if (wv == 0) {
    float p0 = 0, p1 = 0;
#pragma unroll 8
    for (int d = 0; d < 64; d++) {
      float x = W1[d * 64 + lane];
      p0 = fmaf(x, a1[d], p0); p1 = fmaf(x, a1[64 + d], p1);
    }
    v_sh[0][lane] = p0; v_sh[1][lane] = p1;
  } else if (wv == 1) {
    float p0 = 0, p1 = 0;
#pragma unroll 8
    for (int d = 0; d < 64; d++) {
      float x = W2[d * 64 + lane];
      p0 = fmaf(x, a2[d], p0); p1 = fmaf(x, a2[64 + d], p1);
    }
    v_sh[2][lane] = p0; v_sh[3][lane] = p1;
  } else if (blockIdx.x == 0 && wv == 2) {
    float p = 0;
#pragma unroll 8
    for (int d = 0; d < 64; d++) p = fmaf(W1[d * 64 + lane], a1[128 + d], p);
    vi_sh[0][lane] = p;
  } else if (blockIdx.x == 0 && wv == 3) {
    float p = 0;
#pragma unroll 8
    for (int d = 0; d < 64; d++) p = fmaf(W2[d * 64 + lane], a2[128 + d], p);
    vi_sh[1][lane] = p;
  }
  __syncthreads();

  if (node >= 2 && node <= 201) {
    int i = node - 2;
    float a = u * y;
    ((unsigned short*)(ws + WS_UB))[(size_t)(b * NI + i) * 64 + lane] =
        (unsigned short)f2bf(a);
    float p0 = a * v_sh[0][lane], p1 = a * v_sh[1][lane];
    float p2 = a * v_sh[2][lane], p3 = a * v_sh[3][lane];
    reduce4(p0, p1, p2, p3);
    if (lane == 0) {
      f32x4 sc = {p0, p1, p2, p3};
      *(f32x4*)(ws + WS_SC + (size_t)(b * NIP + i) * 4) = sc;
    }
  }
  if (blockIdx.x == 0 && wv == 0) {
    float q0 = iid_sh[lane] * vi_sh[0][lane];
    float q1 = iid_sh[lane] * vi_sh[1][lane];
    reduce2(q0, q1);
    if (lane == 0) { ws[WS_T + b * 2] = q0; ws[WS_T + b * 2 + 1] = q1; }
  }
  if (blockIdx.x == 0 && b == 0 && wv == 1) {
    float c0 = reduce1(W1b[lane] * a1[lane]);
    float c1 = reduce1(W1b[lane] * a1[64 + lane]);
    float c2 = reduce1(W1b[lane] * a1[128 + lane]);
    float c3 = reduce1(W2b[lane] * a2[lane]);
    float c4 = reduce1(W2b[lane] * a2[64 + lane]);
    float c5 = reduce1(W2b[lane] * a2[128 + lane]);
    if (lane == 0) {
      ws[WS_CR + 0] = c0; ws[WS_CR + 1] = c1; ws[WS_CR + 2] = c2;
      ws[WS_CR + 3] = c3; ws[WS_CR + 4] = c4; ws[WS_CR + 5] = c5;
    }
  }
}

// kY: grid (13, BB) x 256: stage bf16 frags, in-block softmax stats, MFMA
// S/T + epilogue -> g, MFMA H, output.
__global__ void __launch_bounds__(256) gat_kY(const float* __restrict__ ws,
                                              const float* __restrict__ lw,
                                              const float* __restrict__ lb,
                                              const float* __restrict__ a1b,
                                              const float* __restrict__ a2b,
                                              float* __restrict__ out) {
  int b = blockIdx.y, jt = blockIdx.x, tid = threadIdx.x;
  int wv = tid >> 6, lane = tid & 63, q = lane >> 4, col = lane & 15;
  __shared__ __align__(16) short sUA[13 * 2 * 64 * 8];   // node-major frags
  __shared__ __align__(16) short sUAT[7 * 4 * 64 * 8];   // d-major B frags
  __shared__ __align__(16) short sG[7 * 64 * 8];         // g A-frags
  __shared__ float sPart[4][2][16];
  __shared__ float sST[NIP][6];    // base1,rm1,iv1,base2,rm2,iv2 per i
  __shared__ float skv[2][NIP];    // sk' per head (pads garbage-but-finite)
  __shared__ float wmx[4][2];

  const unsigned short* uwb =
      (const unsigned short*)(ws + WS_UB) + (size_t)b * NI * 64;

  // stage node-major frags (pure 16B copies, no cvt)
  for (int idx = tid; idx < 13 * 2 * 64; idx += 256) {
    int itile = idx >> 7, rem = idx & 127, kh = rem >> 6, ln = rem & 63;
    int node = itile * 16 + (ln & 15);
    int dbase = kh * 32 + (ln >> 4) * 8;
    bf16x8 pk;
    if (node < NI) pk = *(const bf16x8*)(uwb + node * 64 + dbase);
    else {
#pragma unroll
      for (int k = 0; k < 8; k++) pk[k] = 0;
    }
    *(bf16x8*)(sUA + idx * 8) = pk;
  }
  // stage d-major B frags
  {
    int d = tid & 63, ir = tid >> 6;
#pragma unroll
    for (int p = 0; p < 7; p++) {
      int i0 = p * 32 + ir * 8;
      bf16x8 pk;
#pragma unroll
      for (int u = 0; u < 8; u++)
        pk[u] = (i0 + u < NI) ? (short)uwb[(i0 + u) * 64 + d] : (short)0;
      int off = ((p * 4 + (d >> 4)) * 64 + ((d & 15) + 16 * ir)) * 8;
      *(bf16x8*)(sUAT + off) = pk;
    }
  }
  ((int*)(sG + (6 * 64 + 32) * 8))[tid] = 0;

  // consts + per-i raw scores -> skv/base
  float c0 = ws[WS_CR + 0], c1 = ws[WS_CR + 1], c2 = ws[WS_CR + 2];
  float c3 = ws[WS_CR + 3], c4 = ws[WS_CR + 4], c5 = ws[WS_CR + 5];
  float t1 = ws[WS_T + b * 2] + c2 + a1b[0];
  float t2 = ws[WS_T + b * 2 + 1] + c5 + a2b[0];
  float base1 = 0, base2 = 0;
  if (tid < NIP) {
    f32x4 sc = *(const f32x4*)(ws + WS_SC + (size_t)(b * NIP + tid) * 4);
    base1 = sc.x + c0 + t1;
    base2 = sc.z + c3 + t2;
    skv[0][tid] = sc.y + c1;
    skv[1][tid] = sc.w + c4;
  }
  __syncthreads();

  // block max over real j
  float m1 = (tid < NI) ? skv[0][tid] : -3e38f;
  float m2 = (tid < NI) ? skv[1][tid] : -3e38f;
  rmax2(m1, m2);
  if (lane == 0) { wmx[wv][0] = m1; wmx[wv][1] = m2; }
  __syncthreads();

  // per-i stats (redundant per block; exp-bound ~0.9us)
  if (tid < NIP) {
    float rm1 = 0, iv1 = 0, rm2 = 0, iv2 = 0, b1 = 0, b2 = 0;
    if (tid < NI) {
      float mx1 = fmaxf(fmaxf(wmx[0][0], wmx[1][0]), fmaxf(wmx[2][0], wmx[3][0]));
      float mx2 = fmaxf(fmaxf(wmx[0][1], wmx[1][1]), fmaxf(wmx[2][1], wmx[3][1]));
      b1 = base1; b2 = base2;
      rm1 = leaky(base1 + mx1);   // leaky monotone
      rm2 = leaky(base2 + mx2);
      float d1 = 0, d2 = 0;
#pragma unroll 4
      for (int j = 0; j < NI; j++) {
        float s1 = base1 + skv[0][j];
        d1 += __expf(fmaxf(s1, 0.01f * s1) - rm1);
        float s2 = base2 + skv[1][j];
        d2 += __expf(fmaxf(s2, 0.01f * s2) - rm2);
      }
      iv1 = 1.0f / d1; iv2 = 1.0f / d2;
    }
    sST[tid][0] = b1; sST[tid][1] = rm1; sST[tid][2] = iv1;
    sST[tid][3] = b2; sST[tid][4] = rm2; sST[tid][5] = iv2;
  }
  __syncthreads();

  // phase A: S,T MFMAs + epilogue -> g
  bf16x8 bf0 = *(bf16x8*)(sUA + ((jt * 2 + 0) * 64 + lane) * 8);
  bf16x8 bf1 = *(bf16x8*)(sUA + ((jt * 2 + 1) * 64 + lane) * 8);
  bf16x8 b2f0 = sq8(bf0), b2f1 = sq8(bf1);
  int jglob = jt * 16 + col;
  float skj1 = skv[0][jglob], skj2 = skv[1][jglob];
  float mpart = 0.f, spart = 0.f;

  for (int it = wv; it < 13; it += 4) {
    bf16x8 af0 = *(bf16x8*)(sUA + ((it * 2 + 0) * 64 + lane) * 8);
    bf16x8 af1 = *(bf16x8*)(sUA + ((it * 2 + 1) * 64 + lane) * 8);
    bf16x8 a2f0 = sq8(af0), a2f1 = sq8(af1);
    f32x4 s = {0, 0, 0, 0}, t = {0, 0, 0, 0};
    s = __builtin_amdgcn_mfma_f32_16x16x32_bf16(af0, bf0, s, 0, 0, 0);
    s = __builtin_amdgcn_mfma_f32_16x16x32_bf16(af1, bf1, s, 0, 0, 0);
    t = __builtin_amdgcn_mfma_f32_16x16x32_bf16(a2f0, b2f0, t, 0, 0, 0);
    t = __builtin_amdgcn_mfma_f32_16x16x32_bf16(a2f1, b2f1, t, 0, 0, 0);
    bf16x4 gp;
#pragma unroll
    for (int r = 0; r < 4; r++) {
      int i = it * 16 + q * 4 + r;
      float bb1 = sST[i][0], rr1 = sST[i][1], vv1 = sST[i][2];
      float bb2 = sST[i][3], rr2 = sST[i][4], vv2 = sST[i][5];
      float mu = s[r] * (1.f / 64);
      float var = fmaxf(t[r] * (1.f / 64) - mu * mu, 0.f);
      float inv = rsqrtf(var + LN_EPS);
      float sc1 = bb1 + skj1;
      float e1 = __expf(fmaxf(sc1, 0.01f * sc1) - rr1) * vv1;
      float sc2 = bb2 + skj2;
      float e2 = __expf(fmaxf(sc2, 0.01f * sc2) - rr2) * vv2;
      float c = 0.5f * (e1 + e2);
      float g = c * inv;
      mpart = fmaf(g, mu, mpart);
      spart += c;
      gp[r] = f2bf(g);
    }
    int kl = (it & 1) * 16 + q * 4;
    int off = ((it >> 1) * 64 + (col + 16 * (kl >> 3))) * 8 + (kl & 7);
    *(bf16x4*)(sG + off) = gp;
  }
  mpart += __shfl_xor(mpart, 16, 64); mpart += __shfl_xor(mpart, 32, 64);
  spart += __shfl_xor(spart, 16, 64); spart += __shfl_xor(spart, 32, 64);
  if (lane < 16) { sPart[wv][0][lane] = mpart; sPart[wv][1][lane] = spart; }
  __syncthreads();

  // phase B: H = G^T * UA
  f32x4 acc = {0, 0, 0, 0};
#pragma unroll
  for (int kt = 0; kt < 7; kt++) {
    bf16x8 ga = *(bf16x8*)(sG + (kt * 64 + lane) * 8);
    bf16x8 ub = *(bf16x8*)(sUAT + ((kt * 4 + wv) * 64 + lane) * 8);
    acc = __builtin_amdgcn_mfma_f32_16x16x32_bf16(ga, ub, acc, 0, 0, 0);
  }
  int d = wv * 16 + col;
  float w = lw[d], bia = lb[d];
#pragma unroll
  for (int r = 0; r < 4; r++) {
    int jl = q * 4 + r, jg = jt * 16 + jl;
    if (jg < NI) {
      float m = sPart[0][0][jl] + sPart[1][0][jl] + sPart[2][0][jl] + sPart[3][0][jl];
      float S = sPart[0][1][jl] + sPart[1][1][jl] + sPart[2][1][jl] + sPart[3][1][jl];
      float uajd = bf2fs((short)uwb[jg * 64 + d]);
      float att = w * (uajd * acc[r] - m) + bia * S;
      out[(size_t)(b * 201 + 1 + jg) * 64 + d] = leaky(att);
    }
  }
}

extern "C" void kernel_launch(void* const* d_in, const int* in_sizes, int n_in,
                              void* d_out, int out_size, void* d_ws, size_t ws_size,
                              hipStream_t stream) {
  const float* emb = (const float*)d_in[0];
  const float* lw  = (const float*)d_in[1];
  const float* lb  = (const float*)d_in[2];
  const float* W1  = (const float*)d_in[3];
  const float* W1b = (const float*)d_in[4];
  const float* W2  = (const float*)d_in[5];
  const float* W2b = (const float*)d_in[6];
  const float* a1  = (const float*)d_in[7];
  const float* a1b = (const float*)d_in[8];
  const float* a2  = (const float*)d_in[9];
  const float* a2b = (const float*)d_in[10];
  float* ws = (float*)d_ws;
  float* out = (float*)d_out;

  gat_kX<<<dim3(51, BB), dim3(256), 0, stream>>>(emb, lw, lb, W1, W1b, W2, W2b,
                                                 a1, a2, ws, out);
  gat_kY<<<dim3(13, BB), dim3(256), 0, stream>>>(ws, lw, lb, a1b, a2b, out);
}